// Round 1
// baseline (120.631 us; speedup 1.0000x reference)
//
#include <hip/hip_runtime.h>

// Problem constants (fixed by reference setup_inputs)
constexpr int B  = 32;
constexpr int S  = 32;
constexpr int W  = 30;
constexpr int E  = 300;
constexpr int EV = E / 4;            // 75 float4 per embedding row (1200 B, 16B-aligned)
constexpr int NSENT = B * S;         // 1024 sentences

// Output layout in d_out (flat f32, reference return order):
constexpr long OFF_EMB   = 0;                                  // [1024,30,300]
constexpr long OFF_SHARE = (long)NSENT * W * E;                // 9,216,000  [32,960,300] (same flat order)
constexpr long OFF_MASK  = OFF_SHARE + (long)NSENT * W * E;    // 18,432,000 [32,960]
constexpr long OFF_WM    = OFF_MASK + (long)NSENT * W;         // 18,462,720 [1024,30]
constexpr long OFF_SM    = OFF_WM + (long)NSENT * W;           // 18,493,440 [32,32]

__global__ __launch_bounds__(256) void embed_gather_kernel(
    const int* __restrict__ input,      // [1024*30] token ids
    const float* __restrict__ Wemb,     // [50000*300]
    float* __restrict__ out)
{
    const int sent = blockIdx.x;        // 0..1023
    const int tid  = threadIdx.x;

    __shared__ int idx_s[W];            // raw token ids for this sentence
    __shared__ int tidx_s[W];           // truncated-at-first-zero ids (temp)
    __shared__ int zpos_s;              // first-zero position (W if none)

    if (tid < W) idx_s[tid] = input[sent * W + tid];
    __syncthreads();

    if (tid == 0) {
        int z = W;
        int any = 0;
        for (int k = 0; k < W; ++k) {
            int v = idx_s[k];
            any |= (v != 0);
            if (v == 0 && z == W) z = k;
        }
        zpos_s = z;
        out[OFF_SM + sent] = any ? 1.0f : 0.0f;   // sent_mask
    }
    __syncthreads();

    const int z = zpos_s;
    if (tid < W) {
        int idx = idx_s[tid];
        int tix = (tid < z) ? idx : 0;            // cumprod-keep semantics
        tidx_s[tid] = tix;
        out[OFF_WM   + (long)sent * W + tid] = (idx != 0) ? 1.0f : 0.0f;  // word_mask
        out[OFF_MASK + (long)sent * W + tid] = (tix != 0) ? 1.0f : 0.0f;  // mask
    }
    __syncthreads();

    // Gather both embedding outputs. Each row = 75 float4; 30*75 = 2250 work items.
    const float4* __restrict__ W4 = (const float4*)Wemb;
    float4* __restrict__ oe = (float4*)(out + OFF_EMB);
    float4* __restrict__ os = (float4*)(out + OFF_SHARE);
    const long sbase = (long)sent * W * EV;

    for (int i = tid; i < W * EV; i += 256) {
        int k = i / EV;                 // word within sentence
        int q = i - k * EV;             // float4 within row
        int idx = idx_s[k];
        int tix = tidx_s[k];
        float4 a = W4[(long)idx * EV + q];
        float4 b = (tix == idx) ? a : W4[(long)tix * EV + q];
        oe[sbase + i] = a;
        os[sbase + i] = b;
    }
}

extern "C" void kernel_launch(void* const* d_in, const int* in_sizes, int n_in,
                              void* d_out, int out_size, void* d_ws, size_t ws_size,
                              hipStream_t stream) {
    const int*   input = (const int*)d_in[0];     // [32,32,30] token ids
    const float* Wemb  = (const float*)d_in[1];   // [50000,300]
    float*       out   = (float*)d_out;

    embed_gather_kernel<<<NSENT, 256, 0, stream>>>(input, Wemb, out);
}